// Round 1
// baseline (518.885 us; speedup 1.0000x reference)
//
#include <hip/hip_runtime.h>
#include <cstdint>
#include <cstddef>

#define D_MODEL 2048
#define T_SEQ   2048
#define BATCH   2
#define N_HEADS 16
#define KV_HEADS 4
#define HEAD_DIM 128
#define QKV_N   3072          // D_MODEL + 2*512
#define ROWS    (BATCH * T_SEQ) // 4096

typedef float  floatx4 __attribute__((ext_vector_type(4)));
typedef short  shortx8 __attribute__((ext_vector_type(8)));
typedef __bf16 bf16x8  __attribute__((ext_vector_type(8)));

typedef const void __attribute__((address_space(1))) gvoid_t;
typedef void __attribute__((address_space(3)))       svoid_t;

__device__ __forceinline__ floatx4 mfma16(shortx8 a, shortx8 b, floatx4 c) {
  return __builtin_amdgcn_mfma_f32_16x16x32_bf16(
      __builtin_bit_cast(bf16x8, a), __builtin_bit_cast(bf16x8, b), c, 0, 0, 0);
}

__device__ __forceinline__ unsigned short f2bf(float f) {
  union { float f; unsigned int u; } v; v.f = f;
  unsigned int u = v.u;
  u += 0x7fffu + ((u >> 16) & 1u);   // RNE
  return (unsigned short)(u >> 16);
}

// ---------------- fp32 -> bf16 elementwise (x) ----------------
__global__ void cvt_x(const float* __restrict__ in, unsigned short* __restrict__ out, int n4) {
  int i = blockIdx.x * blockDim.x + threadIdx.x;
  if (i >= n4) return;
  float4 v = ((const float4*)in)[i];
  ushort4 o;
  o.x = f2bf(v.x); o.y = f2bf(v.y); o.z = f2bf(v.z); o.w = f2bf(v.w);
  ((ushort4*)out)[i] = o;
}

// ---------------- fp32 W[K][N] -> bf16 Wt[N][K] ----------------
__global__ void transpose_cvt(const float* __restrict__ W, unsigned short* __restrict__ Wt,
                              int K, int N) {
  __shared__ float tile[32][33];
  int n0 = blockIdx.x * 32, k0 = blockIdx.y * 32;
  int tx = threadIdx.x, ty = threadIdx.y;   // (32, 8)
  #pragma unroll
  for (int i = 0; i < 32; i += 8)
    tile[ty + i][tx] = W[(size_t)(k0 + ty + i) * N + n0 + tx];
  __syncthreads();
  #pragma unroll
  for (int i = 0; i < 32; i += 8)
    Wt[(size_t)(n0 + ty + i) * K + k0 + tx] = f2bf(tile[tx][ty + i]);
}

// ---------------- bf16 V slice of qkv -> Vt (B,KVH,HEAD_DIM,T) ----------------
__global__ void build_vt(const unsigned short* __restrict__ qkv, unsigned short* __restrict__ vt) {
  __shared__ unsigned short tile[32][33];
  int t0  = blockIdx.x * 32;
  int d0  = (blockIdx.y & 3) * 32;
  int kvh = blockIdx.y >> 2;
  int b   = blockIdx.z;
  int tx = threadIdx.x, ty = threadIdx.y;   // (32, 8)
  #pragma unroll
  for (int i = 0; i < 32; i += 8)
    tile[ty + i][tx] = qkv[(size_t)(b * T_SEQ + t0 + ty + i) * QKV_N
                           + D_MODEL + 512 + kvh * HEAD_DIM + d0 + tx];
  __syncthreads();
  #pragma unroll
  for (int i = 0; i < 32; i += 8)
    vt[((size_t)(b * KV_HEADS + kvh) * HEAD_DIM + d0 + ty + i) * T_SEQ + t0 + tx]
        = tile[tx][ty + i];
}

// ---------------- bf16 GEMM: C[M][N] = A[M][K] * Bt[N][K]^T + bias ----------------
// m97 structure: 128x128 tile, BK=32, global_load_lds(16B), swizzled LDS [k8][row][8]
__global__ __launch_bounds__(256) void gemm_bt(
    const unsigned short* __restrict__ A,
    const unsigned short* __restrict__ Bt,
    const float* __restrict__ bias,
    void* __restrict__ Cout,
    int M, int N, int K, int c_bf16)
{
  __shared__ __align__(16) unsigned short sA[4 * 128 * 8];
  __shared__ __align__(16) unsigned short sB[4 * 128 * 8];
  const int tid  = threadIdx.x;
  const int wave = tid >> 6, lane = tid & 63;
  const int quad = lane >> 4, l16 = lane & 15;
  const int bm = blockIdx.y * 128, bn = blockIdx.x * 128;
  const int wm = (wave >> 1) * 64, wn = (wave & 1) * 64;
  floatx4 acc[4][4] = {};

  const int idx0 = tid, idx1 = 256 + tid;
  const int k8_0 = idx0 >> 7, r_0 = idx0 & 127;
  const int k8_1 = idx1 >> 7, r_1 = idx1 & 127;
  const unsigned short* a0 = A  + (size_t)(bm + r_0) * K + k8_0 * 8;
  const unsigned short* a1 = A  + (size_t)(bm + r_1) * K + k8_1 * 8;
  const unsigned short* b0 = Bt + (size_t)(bn + r_0) * K + k8_0 * 8;
  const unsigned short* b1 = Bt + (size_t)(bn + r_1) * K + k8_1 * 8;
  unsigned short* ldsA0 = &sA[(0 * 256 + wave * 64) * 8];
  unsigned short* ldsA1 = &sA[(1 * 256 + wave * 64) * 8];
  unsigned short* ldsB0 = &sB[(0 * 256 + wave * 64) * 8];
  unsigned short* ldsB1 = &sB[(1 * 256 + wave * 64) * 8];

  for (int k0 = 0; k0 < K; k0 += 32) {
    __syncthreads();
    __builtin_amdgcn_global_load_lds((gvoid_t*)(a0 + k0), (svoid_t*)ldsA0, 16, 0, 0);
    __builtin_amdgcn_global_load_lds((gvoid_t*)(a1 + k0), (svoid_t*)ldsA1, 16, 0, 0);
    __builtin_amdgcn_global_load_lds((gvoid_t*)(b0 + k0), (svoid_t*)ldsB0, 16, 0, 0);
    __builtin_amdgcn_global_load_lds((gvoid_t*)(b1 + k0), (svoid_t*)ldsB1, 16, 0, 0);
    __syncthreads();

    shortx8 af[4], bfq[4];
    #pragma unroll
    for (int mi = 0; mi < 4; ++mi)
      af[mi] = *(const shortx8*)&sA[(quad * 128 + wm + mi * 16 + l16) * 8];
    #pragma unroll
    for (int ni = 0; ni < 4; ++ni)
      bfq[ni] = *(const shortx8*)&sB[(quad * 128 + wn + ni * 16 + l16) * 8];
    #pragma unroll
    for (int mi = 0; mi < 4; ++mi)
      #pragma unroll
      for (int ni = 0; ni < 4; ++ni)
        acc[mi][ni] = mfma16(af[mi], bfq[ni], acc[mi][ni]);
  }

  #pragma unroll
  for (int mi = 0; mi < 4; ++mi) {
    #pragma unroll
    for (int ni = 0; ni < 4; ++ni) {
      const int row = bm + wm + mi * 16 + quad * 4;
      const int col = bn + wn + ni * 16 + l16;
      const float bv = bias[col];
      #pragma unroll
      for (int r = 0; r < 4; ++r) {
        float v = acc[mi][ni][r] + bv;
        if (c_bf16)
          ((unsigned short*)Cout)[(size_t)(row + r) * N + col] = f2bf(v);
        else
          ((float*)Cout)[(size_t)(row + r) * N + col] = v;
      }
    }
  }
}

// ---------------- flash attention, GQA, causal ----------------
// grid (T/64, N_HEADS, B), block 256 (4 waves x 16 Q-rows each), 64-key tiles
__global__ __launch_bounds__(256) void attn_kernel(
    const unsigned short* __restrict__ qkv,   // (B*T, 3072) bf16
    const unsigned short* __restrict__ vt,    // (B,KVH,HEAD_DIM,T) bf16
    unsigned short* __restrict__ aout)        // (B*T, D_MODEL) bf16
{
  __shared__ __align__(16) unsigned short sQ[64][136];
  __shared__ __align__(16) unsigned short sK[64][136];
  __shared__ __align__(16) unsigned short sV[128][80];
  __shared__ __align__(16) unsigned short sP[4][16][80];

  const int tid  = threadIdx.x;
  const int wave = tid >> 6, lane = tid & 63;
  const int quad = lane >> 4, l16 = lane & 15;
  const int qt = blockIdx.x, head = blockIdx.y, b = blockIdx.z;
  const int kvh = head >> 2;
  const int q0 = qt * 64;
  const float scale = 0.08838834764831845f;   // 1/sqrt(128)
  const float L2E = 1.4426950408889634f;

  #pragma unroll
  for (int it = 0; it < 4; ++it) {
    int idx = it * 256 + tid;
    int r = idx >> 4, c8 = idx & 15;
    *(uint4*)&sQ[r][c8 * 8] =
        *(const uint4*)(qkv + (size_t)(b * T_SEQ + q0 + r) * QKV_N + head * HEAD_DIM + c8 * 8);
  }

  float m_i[4], l_i[4];
  #pragma unroll
  for (int r = 0; r < 4; ++r) { m_i[r] = -__builtin_inff(); l_i[r] = 0.f; }
  floatx4 o_acc[8] = {};

  for (int kt = 0; kt <= qt; ++kt) {
    const int kb = kt * 64;
    __syncthreads();
    #pragma unroll
    for (int it = 0; it < 4; ++it) {
      int idx = it * 256 + tid;
      int r = idx >> 4, c8 = idx & 15;
      *(uint4*)&sK[r][c8 * 8] =
          *(const uint4*)(qkv + (size_t)(b * T_SEQ + kb + r) * QKV_N
                          + D_MODEL + kvh * HEAD_DIM + c8 * 8);
    }
    #pragma unroll
    for (int it = 0; it < 4; ++it) {
      int idx = it * 256 + tid;
      int d = idx >> 3, c8 = idx & 7;
      *(uint4*)&sV[d][c8 * 8] =
          *(const uint4*)(vt + ((size_t)(b * KV_HEADS + kvh) * HEAD_DIM + d) * T_SEQ + kb + c8 * 8);
    }
    __syncthreads();

    // S = Q K^T for this wave's 16 rows x 64 keys
    floatx4 s[4] = {};
    #pragma unroll
    for (int ks = 0; ks < 4; ++ks) {
      shortx8 qf = *(const shortx8*)&sQ[wave * 16 + l16][ks * 32 + quad * 8];
      #pragma unroll
      for (int ct = 0; ct < 4; ++ct) {
        shortx8 kf = *(const shortx8*)&sK[ct * 16 + l16][ks * 32 + quad * 8];
        s[ct] = mfma16(qf, kf, s[ct]);
      }
    }

    // scale + causal mask (C-layout: row = quad*4+r, col = ct*16+l16)
    const int qrow = q0 + wave * 16 + quad * 4;
    #pragma unroll
    for (int ct = 0; ct < 4; ++ct) {
      const int kcol = kb + ct * 16 + l16;
      #pragma unroll
      for (int r = 0; r < 4; ++r) {
        float v = s[ct][r] * scale;
        s[ct][r] = (kcol <= qrow + r) ? v : -__builtin_inff();
      }
    }

    // online softmax (per-row stats shared by the 16 lanes of each quad)
    #pragma unroll
    for (int r = 0; r < 4; ++r) {
      float mx = fmaxf(fmaxf(s[0][r], s[1][r]), fmaxf(s[2][r], s[3][r]));
      mx = fmaxf(mx, __shfl_xor(mx, 1));
      mx = fmaxf(mx, __shfl_xor(mx, 2));
      mx = fmaxf(mx, __shfl_xor(mx, 4));
      mx = fmaxf(mx, __shfl_xor(mx, 8));
      const float newm = fmaxf(m_i[r], mx);
      float sum = 0.f;
      #pragma unroll
      for (int ct = 0; ct < 4; ++ct) {
        float p = exp2f((s[ct][r] - newm) * L2E);
        s[ct][r] = p;
        sum += p;
      }
      sum += __shfl_xor(sum, 1);
      sum += __shfl_xor(sum, 2);
      sum += __shfl_xor(sum, 4);
      sum += __shfl_xor(sum, 8);
      const float alpha = exp2f((m_i[r] - newm) * L2E);
      l_i[r] = l_i[r] * alpha + sum;
      m_i[r] = newm;
      #pragma unroll
      for (int nt = 0; nt < 8; ++nt) o_acc[nt][r] *= alpha;
    }

    // P: C-layout -> A-layout via LDS (per-wave region)
    #pragma unroll
    for (int ct = 0; ct < 4; ++ct)
      #pragma unroll
      for (int r = 0; r < 4; ++r)
        sP[wave][quad * 4 + r][ct * 16 + l16] = f2bf(s[ct][r]);
    __syncthreads();

    // O += P V
    #pragma unroll
    for (int ks = 0; ks < 2; ++ks) {
      shortx8 pf = *(const shortx8*)&sP[wave][l16][ks * 32 + quad * 8];
      #pragma unroll
      for (int nt = 0; nt < 8; ++nt) {
        shortx8 vf = *(const shortx8*)&sV[nt * 16 + l16][ks * 32 + quad * 8];
        o_acc[nt] = mfma16(pf, vf, o_acc[nt]);
      }
    }
  }

  const int trow = q0 + wave * 16 + quad * 4;
  #pragma unroll
  for (int r = 0; r < 4; ++r) {
    const float inv = 1.f / l_i[r];
    #pragma unroll
    for (int nt = 0; nt < 8; ++nt) {
      aout[(size_t)(b * T_SEQ + trow + r) * D_MODEL + head * HEAD_DIM + nt * 16 + l16] =
          f2bf(o_acc[nt][r] * inv);
    }
  }
}

extern "C" void kernel_launch(void* const* d_in, const int* in_sizes, int n_in,
                              void* d_out, int out_size, void* d_ws, size_t ws_size,
                              hipStream_t stream) {
  const float* x      = (const float*)d_in[0];
  // d_in[1] = attn_mask (causal; unused)
  const float* qkv_w  = (const float*)d_in[2];
  const float* qkv_b  = (const float*)d_in[3];
  const float* proj_w = (const float*)d_in[4];
  const float* proj_b = (const float*)d_in[5];
  float* out = (float*)d_out;

  char* ws = (char*)d_ws;
  // layout (bytes): x_bf16/attn_out alias [0,16M), qkvw_t [16M,28M),
  // projw_t [28M,36M), qkv_bf16 [36M,60M), vt [60M,64M)
  unsigned short* x_bf    = (unsigned short*)(ws);
  unsigned short* qkvw_t  = (unsigned short*)(ws + (size_t)16777216);
  unsigned short* projw_t = (unsigned short*)(ws + (size_t)29360128);
  unsigned short* qkvbuf  = (unsigned short*)(ws + (size_t)37748736);
  unsigned short* vtbuf   = (unsigned short*)(ws + (size_t)62914560);
  unsigned short* attn_out = x_bf;   // safe alias: x_bf dead after GEMM1

  cvt_x<<<(ROWS * D_MODEL / 4 + 255) / 256, 256, 0, stream>>>(x, x_bf, ROWS * D_MODEL / 4);
  transpose_cvt<<<dim3(QKV_N / 32, D_MODEL / 32), dim3(32, 8), 0, stream>>>(qkv_w, qkvw_t, D_MODEL, QKV_N);
  transpose_cvt<<<dim3(D_MODEL / 32, D_MODEL / 32), dim3(32, 8), 0, stream>>>(proj_w, projw_t, D_MODEL, D_MODEL);
  gemm_bt<<<dim3(QKV_N / 128, ROWS / 128), 256, 0, stream>>>(
      x_bf, qkvw_t, qkv_b, (void*)qkvbuf, ROWS, QKV_N, D_MODEL, 1);
  build_vt<<<dim3(T_SEQ / 32, 16, BATCH), dim3(32, 8), 0, stream>>>(qkvbuf, vtbuf);
  attn_kernel<<<dim3(T_SEQ / 64, N_HEADS, BATCH), 256, 0, stream>>>(qkvbuf, vtbuf, attn_out);
  gemm_bt<<<dim3(D_MODEL / 128, ROWS / 128), 256, 0, stream>>>(
      attn_out, projw_t, proj_b, (void*)out, ROWS, D_MODEL, D_MODEL, 0);
}